// Round 9
// baseline (142.678 us; speedup 1.0000x reference)
//
#include <hip/hip_runtime.h>
#include <math.h>

typedef __attribute__((ext_vector_type(8))) short short8x;   // 8 x bf16 = 4 VGPRs
typedef __attribute__((ext_vector_type(4))) float float4x;   // MFMA 16x16 C/D frag
typedef unsigned short u16;
typedef unsigned int u32;

__device__ __forceinline__ float bf2f(u16 u) {
    return __uint_as_float(((u32)u) << 16);
}
__device__ __forceinline__ u16 f2bf(float f) {
    u32 u = __float_as_uint(f);
    u32 r = (u + 0x7fffu + ((u >> 16) & 1u)) >> 16;   // round-to-nearest-even
    return (u16)r;
}
// monotone float<->u32 mapping (u-order == f-order), exact; for atomicMax on floats
__device__ __forceinline__ u32 fenc(float f) {
    u32 b = __float_as_uint(f);
    return b ^ (0x80000000u | (u32)((int)b >> 31));
}
__device__ __forceinline__ float fdec(u32 u) {
    u32 b = (u & 0x80000000u) ? (u ^ 0x80000000u) : ~u;
    return __uint_as_float(b);
}

// ---------------------------------------------------------------- sizes
// B=4, H=W=96, C_in=64, C_hid=256, C_out=64, padded HP=98. c split: 8 groups x 32.
// 5-dispatch pipeline: gl1(+border+gl2init) -> gate1 -> gemm1(fused x-stage, atomic
//                      pool max) -> gate2 -> conv2(full-row waves)
// NOTE (round-5 lesson): h2p border-zero and gl2 init MUST be dispatch-serialized
// before gemm1's writes/atomics.
// ws layout (bytes):
//   h2p   @ 4718592   : 4*8*98*98*32*2= 19,668,992 bf16 [b][g][98][98][32]
//   W1A   @ 24387584  : 4*256*64*2    = 131,072    bf16 [b][oc][c64]
//   W2A   @ 24518656  : 4*8*9*64*32*2 = 1,179,648  bf16 [b][g][k][oc][c32]
//   gl1   @ 25698304  : 4*64*4       = 1,024       fp32 per-(b,c) global max
//   gl2   @ 25796608  : 4*9*256*4    = 36,864      u32 fenc(max) [b][k=ki*3+kj][c]

// blocks 0..255: global max per (b,c); blocks 256..287: h2p border zero + gl2 init
__global__ __launch_bounds__(256) void k_gl1(const float* __restrict__ x, float* __restrict__ gl1,
                                             u32* __restrict__ h2p32, u32* __restrict__ gl2u) {
    if (blockIdx.x >= 256) {                        // border-zero duty (plane bi)
        int t = threadIdx.x;
        int plane_id = blockIdx.x - 256;
        u32* plane = h2p32 + plane_id * (98 * 98 * 16);
        for (int i = t; i < 1568; i += 256) plane[i] = 0u;                  // row 0
        for (int i = t; i < 1568; i += 256) plane[97 * 98 * 16 + i] = 0u;   // row 97
        for (int i = t; i < 3072; i += 256) {                               // cols 0 & 97
            int r = (i >> 5) + 1;
            int p = ((i >> 4) & 1) * 97;
            int w = i & 15;
            plane[(r * 98 + p) * 16 + w] = 0u;
        }
        // gl2 init to u32 0 (== most-negative in fenc order); 9216 u32 over 32 blocks
        for (int i = plane_id * 288 + t; i < (plane_id + 1) * 288; i += 256)
            gl2u[i] = 0u;
        return;
    }
    int b = blockIdx.x >> 6, c = blockIdx.x & 63;
    const float4* p = (const float4*)(x + (b * 64 + c) * 9216);
    float m = -1e30f;
    #pragma unroll
    for (int i = 0; i < 9; i++) {
        float4 v = p[i * 256 + threadIdx.x];
        m = fmaxf(m, fmaxf(fmaxf(v.x, v.y), fmaxf(v.z, v.w)));
    }
    __shared__ float red[256];
    red[threadIdx.x] = m;
    __syncthreads();
    for (int s = 128; s > 0; s >>= 1) {
        if (threadIdx.x < s) red[threadIdx.x] = fmaxf(red[threadIdx.x], red[threadIdx.x + s]);
        __syncthreads();
    }
    if (threadIdx.x == 0) gl1[b * 64 + c] = red[0];
}

// fc1 gating -> W1A[b][oc=256][c=64]; 64 blocks = (b, slice16)
__global__ __launch_bounds__(256) void k_gate1(const float* __restrict__ gl1,
                                               const float* __restrict__ ce, const float* __restrict__ gd,
                                               const float* __restrict__ gd2, const float* __restrict__ ci,
                                               const float* __restrict__ w1, u16* __restrict__ W1A) {
    int b = blockIdx.x >> 4, s = blockIdx.x & 15;
    int t = threadIdx.x;
    __shared__ float rce[64], out1[64], ocp[256];
    float cew = ce[0], gdw = gd[0], gd2w = gd2[0];
    if (t < 64) {
        float r = fmaxf(gl1[b * 64 + t] * cew, 0.f);
        rce[t] = r;
        out1[t] = r * gdw;
    }
    __syncthreads();
    {
        int p = t >> 5, oi = t & 31;
        float sv = 0.f;
        #pragma unroll
        for (int g = 0; g < 8; g++) sv += rce[p * 8 + g] * ci[oi * 8 + g];
        ocp[t] = fmaxf(sv, 0.f) * gd2w;
    }
    __syncthreads();
    u16* Wb = W1A + b * 256 * 64;
    #pragma unroll
    for (int i = 0; i < 4; i++) {
        int idx = s * 1024 + i * 256 + t;
        int o = idx >> 6, c = idx & 63;
        float v = out1[c] + ocp[o];
        float sg = 1.f / (1.f + expf(-v));
        Wb[idx] = f2bf(sg * w1[idx]);
    }
}

// h2p interior = gelu( W1A[b] (256x64) @ x-slab (64 x 48px) ); half-row per block.
// Fused: x load+transpose via LDS slab; 3x3-pool maxes via butterfly + atomicMax(fenc).
__global__ __launch_bounds__(256) void k_gemm1(const u16* __restrict__ W1A, const float* __restrict__ x,
                                               u16* __restrict__ h2p, u32* __restrict__ gl2u) {
    int bi = blockIdx.x;
    int b = bi / 192, rem = bi % 192;
    int y = rem >> 1, half = rem & 1;
    int t = threadIdx.x, wave = t >> 6, lane = t & 63, l15 = lane & 15, quad = lane >> 4;

    __shared__ __align__(16) u16 xs[48 * 72];       // [px][c], row pad 72 (144 B, 16B-mult)
    const float* xb = x + (b * 64) * 9216 + y * 96 + half * 48;
    const float2* xb2 = (const float2*)xb;          // 8B-aligned (all offsets even floats)
    #pragma unroll
    for (int i = 0; i < 6; i++) {
        int idx = i * 256 + t;                      // 1536 = 64c x 24 px-pairs
        int c = idx / 24, px2 = idx - c * 24;
        float2 v = xb2[c * 4608 + px2];
        int px = px2 * 2;
        xs[px * 72 + c] = f2bf(v.x);
        xs[(px + 1) * 72 + c] = f2bf(v.y);
    }
    __syncthreads();

    float4x acc[4][3];
    #pragma unroll
    for (int mt = 0; mt < 4; mt++)
        #pragma unroll
        for (int nt = 0; nt < 3; nt++) acc[mt][nt] = (float4x){0.f, 0.f, 0.f, 0.f};
    const u16* Wb = W1A + b * 256 * 64;
    #pragma unroll
    for (int c0 = 0; c0 < 64; c0 += 32) {
        short8x bfr[3];
        #pragma unroll
        for (int nt = 0; nt < 3; nt++)
            bfr[nt] = *(const short8x*)(xs + (nt * 16 + l15) * 72 + c0 + quad * 8);
        #pragma unroll
        for (int mt = 0; mt < 4; mt++) {
            int oc = wave * 64 + mt * 16 + l15;
            short8x afr = *(const short8x*)(Wb + oc * 64 + c0 + quad * 8);
            #pragma unroll
            for (int nt = 0; nt < 3; nt++)
                acc[mt][nt] = __builtin_amdgcn_mfma_f32_16x16x32_bf16(afr, bfr[nt], acc[mt][nt], 0, 0, 0);
        }
    }
    const float is2 = 0.70710678118654752f;
    float gf[4][3][4];
    #pragma unroll
    for (int mt = 0; mt < 4; mt++) {
        #pragma unroll
        for (int nt = 0; nt < 3; nt++) {
            int xx = half * 48 + nt * 16 + l15;
            int oc0 = wave * 64 + mt * 16 + quad * 4;
            int g = oc0 >> 5, cl = oc0 & 31;
            u16 pk[4];
            #pragma unroll
            for (int r = 0; r < 4; r++) {
                float v = acc[mt][nt][r];
                float gl = 0.5f * v * (1.f + erff(v * is2));   // exact GELU
                gf[mt][nt][r] = gl;
                pk[r] = f2bf(gl);
            }
            u16* dst = h2p + ((((b * 8 + g) * 98 + y + 1) * 98) + xx + 1) * 32 + cl;
            *(ushort4*)dst = make_ushort4(pk[0], pk[1], pk[2], pk[3]);
        }
    }
    // 3x3-pool partial maxes: butterfly over 16 px lanes, then atomicMax(fenc)
    int ki = y >> 5;
    int kA = ki * 3 + (half == 0 ? 0 : 1);
    int kB = ki * 3 + (half == 0 ? 1 : 2);
    #pragma unroll
    for (int mt = 0; mt < 4; mt++) {
        float vA[4], vB[4];
        #pragma unroll
        for (int r = 0; r < 4; r++) {
            if (half == 0) { vA[r] = fmaxf(gf[mt][0][r], gf[mt][1][r]); vB[r] = gf[mt][2][r]; }
            else           { vA[r] = gf[mt][0][r]; vB[r] = fmaxf(gf[mt][1][r], gf[mt][2][r]); }
        }
        #pragma unroll
        for (int m = 1; m < 16; m <<= 1) {
            #pragma unroll
            for (int r = 0; r < 4; r++) {
                vA[r] = fmaxf(vA[r], __shfl_xor(vA[r], m));
                vB[r] = fmaxf(vB[r], __shfl_xor(vB[r], m));
            }
        }
        if (l15 == 0) {
            #pragma unroll
            for (int r = 0; r < 4; r++) {
                int oc = wave * 64 + mt * 16 + quad * 4 + r;
                atomicMax(&gl2u[(b * 9 + kA) * 256 + oc], fenc(vA[r]));
                atomicMax(&gl2u[(b * 9 + kB) * 256 + oc], fenc(vB[r]));
            }
        }
    }
}

// Fused fc2 gating: each of 64 blocks (b,slice) decodes gl2, computes out2/ocp2
// (redundantly per block), writes its W2A slice.
__global__ __launch_bounds__(256) void k_gate2(const u32* __restrict__ gl2u,
                                               const float* __restrict__ ce, const float* __restrict__ gd,
                                               const float* __restrict__ gd2, const float* __restrict__ ci,
                                               const float* __restrict__ w2, u16* __restrict__ W2A) {
    int b = blockIdx.x >> 4, s = blockIdx.x & 15;
    int t = threadIdx.x;
    __shared__ float rce[256][5];
    __shared__ float out2[256][9];
    __shared__ float ocp2[64][9];
    {
        float gl[9];
        #pragma unroll
        for (int k = 0; k < 9; k++) gl[k] = fdec(gl2u[(b * 9 + k) * 256 + t]);
        float r[5];
        #pragma unroll
        for (int n = 0; n < 5; n++) {
            float sv = 0.f;
            #pragma unroll
            for (int k = 0; k < 9; k++) sv += gl[k] * ce[n * 9 + k];
            r[n] = fmaxf(sv, 0.f);
            rce[t][n] = r[n];
        }
        #pragma unroll
        for (int k = 0; k < 9; k++) {
            float sv = 0.f;
            #pragma unroll
            for (int n = 0; n < 5; n++) sv += r[n] * gd[k * 5 + n];
            out2[t][k] = sv;
        }
    }
    __syncthreads();
    if (t < 64) {
        int p = t >> 1, oi = t & 1;
        float rt[5];
        #pragma unroll
        for (int n = 0; n < 5; n++) {
            float sv = 0.f;
            #pragma unroll
            for (int g = 0; g < 8; g++) sv += rce[p * 8 + g][n] * ci[oi * 8 + g];
            rt[n] = fmaxf(sv, 0.f);
        }
        #pragma unroll
        for (int k = 0; k < 9; k++) {
            float sv = 0.f;
            #pragma unroll
            for (int n = 0; n < 5; n++) sv += rt[n] * gd2[k * 5 + n];
            ocp2[t][k] = sv;
        }
    }
    __syncthreads();
    u16* Wb = W2A + b * (8 * 9 * 64 * 32);
    for (int it = 0; it < 36; it++) {
        int flat = s * 9216 + it * 256 + t;
        int cl = flat & 31;
        int o = (flat >> 5) & 63;
        int rest = flat >> 11;           // = g*9 + k
        int k = rest % 9, g = rest / 9;
        int c = g * 32 + cl;
        float v = out2[c][k] + ocp2[o][k];
        float sg = 1.f / (1.f + expf(-v));
        Wb[flat] = f2bf(sg * w2[(o * 256 + c) * 9 + k]);
    }
}

// out[b][oc][y][x] = sum_{g,k,cl} W2A[b][g][k][oc][cl] * h2p[b][g][y+i][x+j][cl]
// Block = (b, y): 384 blocks x 256 thr; wave = 16-oc tile x FULL 96-px row (acc[6]).
// Per g: B slab = rows y..y+2 of the g-plane, CONTIGUOUS 18,816 B -> one coalesced
// copy; A-frags stream from L2-resident W2A, each feeding 6 MFMAs (2x fewer A-loads
// than the px-half split). acc order (g outer, k inner) unchanged -> bitwise-identical.
__global__ __launch_bounds__(256) void k_conv2(const u16* __restrict__ W2A, const u16* __restrict__ h2p,
                                               float* __restrict__ out) {
    int b = blockIdx.x / 96, y = blockIdx.x % 96;
    int t = threadIdx.x, wave = t >> 6, lane = t & 63, l15 = lane & 15, quad = lane >> 4;
    __shared__ __align__(16) u16 Bls[3 * 98 * 32];    // 18,816 B  [i][px 98][cl]
    float4x acc[6];
    #pragma unroll
    for (int nt = 0; nt < 6; nt++) acc[nt] = (float4x){0.f, 0.f, 0.f, 0.f};

    for (int g = 0; g < 8; g++) {
        __syncthreads();
        // stage B: rows y..y+2 contiguous (row stride 98*32 u16) = 1176 uint4
        const uint4* Bs = (const uint4*)(h2p + ((b * 8 + g) * 98 + y) * (98 * 32));
        uint4* Bd = (uint4*)Bls;
        for (int i = t; i < 1176; i += 256) Bd[i] = Bs[i];
        __syncthreads();
        const u16* Wg = W2A + (b * 8 + g) * (9 * 64 * 32);
        #pragma unroll
        for (int k = 0; k < 9; k++) {
            int ki = k / 3, kj = k - ki * 3;
            // A-frag: oc rows [wave*16, +16), one coalesced 1024B global load per wave
            short8x af = *(const short8x*)(Wg + (k * 64 + wave * 16 + l15) * 32 + quad * 8);
            #pragma unroll
            for (int nt = 0; nt < 6; nt++) {
                int pxl = nt * 16 + l15 + kj;      // in [0, 98)
                short8x bf = *(const short8x*)(Bls + (ki * 98 + pxl) * 32 + quad * 8);
                acc[nt] = __builtin_amdgcn_mfma_f32_16x16x32_bf16(af, bf, acc[nt], 0, 0, 0);
            }
        }
    }
    #pragma unroll
    for (int nt = 0; nt < 6; nt++) {
        int xx = nt * 16 + l15;
        #pragma unroll
        for (int r = 0; r < 4; r++) {
            int oc = wave * 16 + quad * 4 + r;
            out[((b * 64 + oc) * 96 + y) * 96 + xx] = acc[nt][r];
        }
    }
}

extern "C" void kernel_launch(void* const* d_in, const int* in_sizes, int n_in,
                              void* d_out, int out_size, void* d_ws, size_t ws_size,
                              hipStream_t stream) {
    const float* x    = (const float*)d_in[0];
    const float* w1   = (const float*)d_in[1];
    const float* ce1  = (const float*)d_in[2];
    const float* gd1  = (const float*)d_in[3];
    const float* gd21 = (const float*)d_in[4];
    const float* ci1  = (const float*)d_in[5];
    const float* w2   = (const float*)d_in[6];
    const float* ce2  = (const float*)d_in[7];
    const float* gd2  = (const float*)d_in[8];
    const float* gd22 = (const float*)d_in[9];
    const float* ci2  = (const float*)d_in[10];
    float* out = (float*)d_out;

    char* ws = (char*)d_ws;
    u16*   h2p  = (u16*)(ws + 4718592);
    u16*   W1A  = (u16*)(ws + 24387584);
    u16*   W2A  = (u16*)(ws + 24518656);
    float* gl1  = (float*)(ws + 25698304);
    u32*   gl2u = (u32*)(ws + 25796608);

    k_gl1  <<<288, 256, 0, stream>>>(x, gl1, (u32*)h2p, gl2u);
    k_gate1<<<64,  256, 0, stream>>>(gl1, ce1, gd1, gd21, ci1, w1, W1A);
    k_gemm1<<<768, 256, 0, stream>>>(W1A, x, h2p, gl2u);
    k_gate2<<<64,  256, 0, stream>>>(gl2u, ce2, gd2, gd22, ci2, w2, W2A);
    k_conv2<<<384, 256, 0, stream>>>(W2A, h2p, out);
}

// Round 10
// 131.449 us; speedup vs baseline: 1.0854x; 1.0854x over previous
//
#include <hip/hip_runtime.h>
#include <math.h>

typedef __attribute__((ext_vector_type(8))) short short8x;   // 8 x bf16 = 4 VGPRs
typedef __attribute__((ext_vector_type(4))) float float4x;   // MFMA 16x16 C/D frag
typedef unsigned short u16;
typedef unsigned int u32;

__device__ __forceinline__ float bf2f(u16 u) {
    return __uint_as_float(((u32)u) << 16);
}
__device__ __forceinline__ u16 f2bf(float f) {
    u32 u = __float_as_uint(f);
    u32 r = (u + 0x7fffu + ((u >> 16) & 1u)) >> 16;   // round-to-nearest-even
    return (u16)r;
}
// monotone float<->u32 mapping (u-order == f-order), exact; for atomicMax on floats
__device__ __forceinline__ u32 fenc(float f) {
    u32 b = __float_as_uint(f);
    return b ^ (0x80000000u | (u32)((int)b >> 31));
}
__device__ __forceinline__ float fdec(u32 u) {
    u32 b = (u & 0x80000000u) ? (u ^ 0x80000000u) : ~u;
    return __uint_as_float(b);
}

// ---------------------------------------------------------------- sizes
// B=4, H=W=96, C_in=64, C_hid=256, C_out=64, padded HP=98. c split: 8 groups x 32.
// 5-dispatch pipeline: gl1(+border+gl2init) -> gate1 -> gemm1(fused x-stage, atomic
//                      pool max) -> gate2 -> conv2(px-half waves + reg-prefetch dbuf)
// NOTE (round-5 lesson): h2p border-zero and gl2 init MUST be dispatch-serialized
// before gemm1's writes/atomics.
// NOTE (round-9 lesson): conv2 is latency-bound — 12 waves/CU (768 blocks) beats
// halved A-traffic at 6 waves/CU. Keep the px-half split.
// ws layout (bytes):
//   h2p   @ 4718592   : 4*8*98*98*32*2= 19,668,992 bf16 [b][g][98][98][32]
//   W1A   @ 24387584  : 4*256*64*2    = 131,072    bf16 [b][oc][c64]
//   W2A   @ 24518656  : 4*8*9*64*32*2 = 1,179,648  bf16 [b][g][k][oc][c32]
//   gl1   @ 25698304  : 4*64*4       = 1,024       fp32 per-(b,c) global max
//   gl2   @ 25796608  : 4*9*256*4    = 36,864      u32 fenc(max) [b][k=ki*3+kj][c]

// blocks 0..255: global max per (b,c); blocks 256..287: h2p border zero + gl2 init
__global__ __launch_bounds__(256) void k_gl1(const float* __restrict__ x, float* __restrict__ gl1,
                                             u32* __restrict__ h2p32, u32* __restrict__ gl2u) {
    if (blockIdx.x >= 256) {                        // border-zero duty (plane bi)
        int t = threadIdx.x;
        int plane_id = blockIdx.x - 256;
        u32* plane = h2p32 + plane_id * (98 * 98 * 16);
        for (int i = t; i < 1568; i += 256) plane[i] = 0u;                  // row 0
        for (int i = t; i < 1568; i += 256) plane[97 * 98 * 16 + i] = 0u;   // row 97
        for (int i = t; i < 3072; i += 256) {                               // cols 0 & 97
            int r = (i >> 5) + 1;
            int p = ((i >> 4) & 1) * 97;
            int w = i & 15;
            plane[(r * 98 + p) * 16 + w] = 0u;
        }
        // gl2 init to u32 0 (== most-negative in fenc order); 9216 u32 over 32 blocks
        for (int i = plane_id * 288 + t; i < (plane_id + 1) * 288; i += 256)
            gl2u[i] = 0u;
        return;
    }
    int b = blockIdx.x >> 6, c = blockIdx.x & 63;
    const float4* p = (const float4*)(x + (b * 64 + c) * 9216);
    float m = -1e30f;
    #pragma unroll
    for (int i = 0; i < 9; i++) {
        float4 v = p[i * 256 + threadIdx.x];
        m = fmaxf(m, fmaxf(fmaxf(v.x, v.y), fmaxf(v.z, v.w)));
    }
    __shared__ float red[256];
    red[threadIdx.x] = m;
    __syncthreads();
    for (int s = 128; s > 0; s >>= 1) {
        if (threadIdx.x < s) red[threadIdx.x] = fmaxf(red[threadIdx.x], red[threadIdx.x + s]);
        __syncthreads();
    }
    if (threadIdx.x == 0) gl1[b * 64 + c] = red[0];
}

// fc1 gating -> W1A[b][oc=256][c=64]; 64 blocks = (b, slice16)
__global__ __launch_bounds__(256) void k_gate1(const float* __restrict__ gl1,
                                               const float* __restrict__ ce, const float* __restrict__ gd,
                                               const float* __restrict__ gd2, const float* __restrict__ ci,
                                               const float* __restrict__ w1, u16* __restrict__ W1A) {
    int b = blockIdx.x >> 4, s = blockIdx.x & 15;
    int t = threadIdx.x;
    __shared__ float rce[64], out1[64], ocp[256];
    float cew = ce[0], gdw = gd[0], gd2w = gd2[0];
    if (t < 64) {
        float r = fmaxf(gl1[b * 64 + t] * cew, 0.f);
        rce[t] = r;
        out1[t] = r * gdw;
    }
    __syncthreads();
    {
        int p = t >> 5, oi = t & 31;
        float sv = 0.f;
        #pragma unroll
        for (int g = 0; g < 8; g++) sv += rce[p * 8 + g] * ci[oi * 8 + g];
        ocp[t] = fmaxf(sv, 0.f) * gd2w;
    }
    __syncthreads();
    u16* Wb = W1A + b * 256 * 64;
    #pragma unroll
    for (int i = 0; i < 4; i++) {
        int idx = s * 1024 + i * 256 + t;
        int o = idx >> 6, c = idx & 63;
        float v = out1[c] + ocp[o];
        float sg = 1.f / (1.f + expf(-v));
        Wb[idx] = f2bf(sg * w1[idx]);
    }
}

// h2p interior = gelu( W1A[b] (256x64) @ x-slab (64 x 48px) ); half-row per block.
// Fused: x load+transpose via LDS slab; 3x3-pool maxes via butterfly + atomicMax(fenc).
__global__ __launch_bounds__(256) void k_gemm1(const u16* __restrict__ W1A, const float* __restrict__ x,
                                               u16* __restrict__ h2p, u32* __restrict__ gl2u) {
    int bi = blockIdx.x;
    int b = bi / 192, rem = bi % 192;
    int y = rem >> 1, half = rem & 1;
    int t = threadIdx.x, wave = t >> 6, lane = t & 63, l15 = lane & 15, quad = lane >> 4;

    __shared__ __align__(16) u16 xs[48 * 72];       // [px][c], row pad 72 (144 B, 16B-mult)
    const float* xb = x + (b * 64) * 9216 + y * 96 + half * 48;
    const float2* xb2 = (const float2*)xb;          // 8B-aligned (all offsets even floats)
    #pragma unroll
    for (int i = 0; i < 6; i++) {
        int idx = i * 256 + t;                      // 1536 = 64c x 24 px-pairs
        int c = idx / 24, px2 = idx - c * 24;
        float2 v = xb2[c * 4608 + px2];
        int px = px2 * 2;
        xs[px * 72 + c] = f2bf(v.x);
        xs[(px + 1) * 72 + c] = f2bf(v.y);
    }
    __syncthreads();

    float4x acc[4][3];
    #pragma unroll
    for (int mt = 0; mt < 4; mt++)
        #pragma unroll
        for (int nt = 0; nt < 3; nt++) acc[mt][nt] = (float4x){0.f, 0.f, 0.f, 0.f};
    const u16* Wb = W1A + b * 256 * 64;
    #pragma unroll
    for (int c0 = 0; c0 < 64; c0 += 32) {
        short8x bfr[3];
        #pragma unroll
        for (int nt = 0; nt < 3; nt++)
            bfr[nt] = *(const short8x*)(xs + (nt * 16 + l15) * 72 + c0 + quad * 8);
        #pragma unroll
        for (int mt = 0; mt < 4; mt++) {
            int oc = wave * 64 + mt * 16 + l15;
            short8x afr = *(const short8x*)(Wb + oc * 64 + c0 + quad * 8);
            #pragma unroll
            for (int nt = 0; nt < 3; nt++)
                acc[mt][nt] = __builtin_amdgcn_mfma_f32_16x16x32_bf16(afr, bfr[nt], acc[mt][nt], 0, 0, 0);
        }
    }
    const float is2 = 0.70710678118654752f;
    float gf[4][3][4];
    #pragma unroll
    for (int mt = 0; mt < 4; mt++) {
        #pragma unroll
        for (int nt = 0; nt < 3; nt++) {
            int xx = half * 48 + nt * 16 + l15;
            int oc0 = wave * 64 + mt * 16 + quad * 4;
            int g = oc0 >> 5, cl = oc0 & 31;
            u16 pk[4];
            #pragma unroll
            for (int r = 0; r < 4; r++) {
                float v = acc[mt][nt][r];
                float gl = 0.5f * v * (1.f + erff(v * is2));   // exact GELU
                gf[mt][nt][r] = gl;
                pk[r] = f2bf(gl);
            }
            u16* dst = h2p + ((((b * 8 + g) * 98 + y + 1) * 98) + xx + 1) * 32 + cl;
            *(ushort4*)dst = make_ushort4(pk[0], pk[1], pk[2], pk[3]);
        }
    }
    // 3x3-pool partial maxes: butterfly over 16 px lanes, then atomicMax(fenc)
    int ki = y >> 5;
    int kA = ki * 3 + (half == 0 ? 0 : 1);
    int kB = ki * 3 + (half == 0 ? 1 : 2);
    #pragma unroll
    for (int mt = 0; mt < 4; mt++) {
        float vA[4], vB[4];
        #pragma unroll
        for (int r = 0; r < 4; r++) {
            if (half == 0) { vA[r] = fmaxf(gf[mt][0][r], gf[mt][1][r]); vB[r] = gf[mt][2][r]; }
            else           { vA[r] = gf[mt][0][r]; vB[r] = fmaxf(gf[mt][1][r], gf[mt][2][r]); }
        }
        #pragma unroll
        for (int m = 1; m < 16; m <<= 1) {
            #pragma unroll
            for (int r = 0; r < 4; r++) {
                vA[r] = fmaxf(vA[r], __shfl_xor(vA[r], m));
                vB[r] = fmaxf(vB[r], __shfl_xor(vB[r], m));
            }
        }
        if (l15 == 0) {
            #pragma unroll
            for (int r = 0; r < 4; r++) {
                int oc = wave * 64 + mt * 16 + quad * 4 + r;
                atomicMax(&gl2u[(b * 9 + kA) * 256 + oc], fenc(vA[r]));
                atomicMax(&gl2u[(b * 9 + kB) * 256 + oc], fenc(vB[r]));
            }
        }
    }
}

// Fused fc2 gating: each of 64 blocks (b,slice) decodes gl2, computes out2/ocp2
// (redundantly per block), writes its W2A slice.
__global__ __launch_bounds__(256) void k_gate2(const u32* __restrict__ gl2u,
                                               const float* __restrict__ ce, const float* __restrict__ gd,
                                               const float* __restrict__ gd2, const float* __restrict__ ci,
                                               const float* __restrict__ w2, u16* __restrict__ W2A) {
    int b = blockIdx.x >> 4, s = blockIdx.x & 15;
    int t = threadIdx.x;
    __shared__ float rce[256][5];
    __shared__ float out2[256][9];
    __shared__ float ocp2[64][9];
    {
        float gl[9];
        #pragma unroll
        for (int k = 0; k < 9; k++) gl[k] = fdec(gl2u[(b * 9 + k) * 256 + t]);
        float r[5];
        #pragma unroll
        for (int n = 0; n < 5; n++) {
            float sv = 0.f;
            #pragma unroll
            for (int k = 0; k < 9; k++) sv += gl[k] * ce[n * 9 + k];
            r[n] = fmaxf(sv, 0.f);
            rce[t][n] = r[n];
        }
        #pragma unroll
        for (int k = 0; k < 9; k++) {
            float sv = 0.f;
            #pragma unroll
            for (int n = 0; n < 5; n++) sv += r[n] * gd[k * 5 + n];
            out2[t][k] = sv;
        }
    }
    __syncthreads();
    if (t < 64) {
        int p = t >> 1, oi = t & 1;
        float rt[5];
        #pragma unroll
        for (int n = 0; n < 5; n++) {
            float sv = 0.f;
            #pragma unroll
            for (int g = 0; g < 8; g++) sv += rce[p * 8 + g][n] * ci[oi * 8 + g];
            rt[n] = fmaxf(sv, 0.f);
        }
        #pragma unroll
        for (int k = 0; k < 9; k++) {
            float sv = 0.f;
            #pragma unroll
            for (int n = 0; n < 5; n++) sv += rt[n] * gd2[k * 5 + n];
            ocp2[t][k] = sv;
        }
    }
    __syncthreads();
    u16* Wb = W2A + b * (8 * 9 * 64 * 32);
    for (int it = 0; it < 36; it++) {
        int flat = s * 9216 + it * 256 + t;
        int cl = flat & 31;
        int o = (flat >> 5) & 63;
        int rest = flat >> 11;           // = g*9 + k
        int k = rest % 9, g = rest / 9;
        int c = g * 32 + cl;
        float v = out2[c][k] + ocp2[o][k];
        float sg = 1.f / (1.f + expf(-v));
        Wb[flat] = f2bf(sg * w2[(o * 256 + c) * 9 + k]);
    }
}

// out[b][oc][y][x] = sum_{g,k,cl} W2A[b][g][k][oc][cl] * h2p[b][g][y+i][x+j][cl]
// Block = (b, y, px-half): 768 blocks x 256 thr (12 waves/CU). B halo slab in LDS
// (3 rows x 50 px x 32c = 9.6 KB), DOUBLE-BUFFERED with register prefetch: g+1's
// slab global-loads issue before compute(g); their vmcnt-wait lands after the
// 27-MFMA burst -> global latency overlapped. One barrier per g-iter.
// A-frags stream from L2-resident W2A (coalesced 1024B wave-loads).
// acc order (g outer, k inner) unchanged -> bitwise-identical output.
__global__ __launch_bounds__(256) void k_conv2(const u16* __restrict__ W2A, const u16* __restrict__ h2p,
                                               float* __restrict__ out) {
    int bi = blockIdx.x;
    int b = bi / 192, rem = bi % 192;
    int y = rem >> 1, half = rem & 1;
    int t = threadIdx.x, wave = t >> 6, lane = t & 63, l15 = lane & 15, quad = lane >> 4;
    __shared__ __align__(16) u16 Bls[2][3 * 50 * 32];   // 2 x 9,600 B  [i][px_local 50][cl]

    // per-thread staging offsets (600 uint4 = 256+256+88; slot 2 valid iff t<88)
    int offs[3];
    #pragma unroll
    for (int j = 0; j < 3; j++) {
        int i = t + j * 256;
        int r = i / 200, c16 = i - r * 200;
        offs[j] = ((y + r) * 98 + half * 48) * 32 + c16 * 8;   // u16 units
    }
    const int plane_sz = 98 * 98 * 32;
    uint4 p0, p1, p2;
    {   // prologue: stage g=0
        const u16* pl = h2p + (b * 8) * plane_sz;
        p0 = *(const uint4*)(pl + offs[0]);
        p1 = *(const uint4*)(pl + offs[1]);
        if (t < 88) p2 = *(const uint4*)(pl + offs[2]);
        uint4* Bd = (uint4*)Bls[0];
        Bd[t] = p0;
        Bd[t + 256] = p1;
        if (t < 88) Bd[t + 512] = p2;
    }

    float4x acc[3];
    #pragma unroll
    for (int nt = 0; nt < 3; nt++) acc[nt] = (float4x){0.f, 0.f, 0.f, 0.f};

    for (int g = 0; g < 8; g++) {
        __syncthreads();                 // buf[g&1] ready for all waves
        if (g < 7) {                     // issue g+1 prefetch (async; waited at write below)
            const u16* pl = h2p + (b * 8 + g + 1) * plane_sz;
            p0 = *(const uint4*)(pl + offs[0]);
            p1 = *(const uint4*)(pl + offs[1]);
            if (t < 88) p2 = *(const uint4*)(pl + offs[2]);
        }
        const u16* Wg = W2A + (b * 8 + g) * (9 * 64 * 32);
        const u16* Bcur = Bls[g & 1];
        #pragma unroll
        for (int k = 0; k < 9; k++) {
            int ki = k / 3, kj = k - ki * 3;
            // A-frag: oc rows [wave*16, +16), one coalesced 1024B global load per wave
            short8x af = *(const short8x*)(Wg + (k * 64 + wave * 16 + l15) * 32 + quad * 8);
            #pragma unroll
            for (int nt = 0; nt < 3; nt++) {
                int pxl = nt * 16 + l15 + kj;      // local px in [0,50)
                short8x bf = *(const short8x*)(Bcur + (ki * 50 + pxl) * 32 + quad * 8);
                acc[nt] = __builtin_amdgcn_mfma_f32_16x16x32_bf16(af, bf, acc[nt], 0, 0, 0);
            }
        }
        if (g < 7) {                     // write prefetched slab to the other buffer
            uint4* Bd = (uint4*)Bls[(g + 1) & 1];
            Bd[t] = p0;
            Bd[t + 256] = p1;
            if (t < 88) Bd[t + 512] = p2;
        }
    }
    #pragma unroll
    for (int nt = 0; nt < 3; nt++) {
        int xx = half * 48 + nt * 16 + l15;
        #pragma unroll
        for (int r = 0; r < 4; r++) {
            int oc = wave * 16 + quad * 4 + r;
            out[((b * 64 + oc) * 96 + y) * 96 + xx] = acc[nt][r];
        }
    }
}

extern "C" void kernel_launch(void* const* d_in, const int* in_sizes, int n_in,
                              void* d_out, int out_size, void* d_ws, size_t ws_size,
                              hipStream_t stream) {
    const float* x    = (const float*)d_in[0];
    const float* w1   = (const float*)d_in[1];
    const float* ce1  = (const float*)d_in[2];
    const float* gd1  = (const float*)d_in[3];
    const float* gd21 = (const float*)d_in[4];
    const float* ci1  = (const float*)d_in[5];
    const float* w2   = (const float*)d_in[6];
    const float* ce2  = (const float*)d_in[7];
    const float* gd2  = (const float*)d_in[8];
    const float* gd22 = (const float*)d_in[9];
    const float* ci2  = (const float*)d_in[10];
    float* out = (float*)d_out;

    char* ws = (char*)d_ws;
    u16*   h2p  = (u16*)(ws + 4718592);
    u16*   W1A  = (u16*)(ws + 24387584);
    u16*   W2A  = (u16*)(ws + 24518656);
    float* gl1  = (float*)(ws + 25698304);
    u32*   gl2u = (u32*)(ws + 25796608);

    k_gl1  <<<288, 256, 0, stream>>>(x, gl1, (u32*)h2p, gl2u);
    k_gate1<<<64,  256, 0, stream>>>(gl1, ce1, gd1, gd21, ci1, w1, W1A);
    k_gemm1<<<768, 256, 0, stream>>>(W1A, x, h2p, gl2u);
    k_gate2<<<64,  256, 0, stream>>>(gl2u, ce2, gd2, gd22, ci2, w2, W2A);
    k_conv2<<<768, 256, 0, stream>>>(W2A, h2p, out);
}